// Round 14
// baseline (63.239 us; speedup 1.0000x reference)
//
#include <hip/hip_runtime.h>

// inputs: [M=4096, N=16384] fp32 logits; targets: [M] int32; k = int(0.01*(N-1)) = 163
#define M        4096
#define N        16384
#define K_SEL    163
#define DELTA_W  5.0f
#define NT       256
#define CAPW     512           // per-row candidate cap (mean 372, sd 19; 7.4 sigma)
#define SCALE    4096.0f       // fixed-point for hard-negative sum (order-independent)
#define THRESH   2.0f          // E[count(x>=2)] = 373 per row; 11 sigma above K_SEL

typedef float vfloat4 __attribute__((ext_vector_type(4)));

// Order-preserving float<->uint32 key (ascending float <-> ascending key)
__device__ __forceinline__ unsigned f2key(float x) {
    unsigned u = __float_as_uint(x);
    return u ^ ((unsigned)((int)u >> 31) | 0x80000000u);
}
__device__ __forceinline__ float key2f(unsigned k) {
    unsigned u = k ^ (~(unsigned)((int)k >> 31) | 0x80000000u);
    return __uint_as_float(u);
}
__device__ __forceinline__ void wave_lgkm_wait() {
    asm volatile("s_waitcnt lgkmcnt(0)" ::: "memory");
}

// ---------- Fused kernel: wave-per-row stream -> direct LDS candidate list ----------
// R13 structure, occupancy raised to 8 blocks/CU (32 waves/CU): VGPR cap 64,
// LDS 12 KiB/block (96 KiB/CU). Streaming consume: ballot -> uniform SGPR count
// -> mbcnt rank -> exec-masked ds_write. No atomics, no shfl chains in the loop.
__global__ __launch_bounds__(NT, 8) void fused_row_loss(
    const float* __restrict__ inp, const int* __restrict__ tgt,
    float* __restrict__ row_loss)
{
    __shared__ unsigned hist_all[4][256];   // wave-private 1 KiB
    __shared__ unsigned list_all[4][CAPW];  // wave-private 2 KiB (keys)
    const int lane = threadIdx.x & 63;
    const int wv   = threadIdx.x >> 6;
    const int row  = blockIdx.x * 4 + wv;
    unsigned* hist = hist_all[wv];
    unsigned* list = list_all[wv];
    const float* rp = inp + (size_t)row * N;
    const vfloat4* rp4 = reinterpret_cast<const vfloat4*>(rp);
    const int target = tgt[row];

    // target position decomposition: element t = it*256 + 4*lane + j
    const int it_t = target >> 8;
    const int l_t  = (target & 255) >> 2;
    const int j_t  = target & 3;

    // ---- Phase 1: stream row; push candidates straight to LDS list ----
    unsigned cnt = 0;                        // wave-uniform running candidate count
    #pragma unroll
    for (int it0 = 0; it0 < 64; it0 += 8) {
        vfloat4 v[8];                        // 8 loads in flight per batch (32 VGPR)
        #pragma unroll
        for (int u = 0; u < 8; ++u) v[u] = rp4[(it0 + u) * 64 + lane];
        #pragma unroll
        for (int u = 0; u < 8; ++u) {
            const int it = it0 + u;
            const bool tgt_here = (it == it_t) && (lane == l_t);
            #pragma unroll
            for (int j = 0; j < 4; ++j) {
                const bool pred = (v[u][j] >= THRESH) && !(tgt_here && j == j_t);
                const unsigned long long bal = __ballot(pred);
                if (pred) {
                    const unsigned rank = __builtin_amdgcn_mbcnt_hi(
                        (unsigned)(bal >> 32),
                        __builtin_amdgcn_mbcnt_lo((unsigned)bal, 0u));
                    const unsigned slot = cnt + rank;
                    if (slot < CAPW) list[slot] = f2key(v[u][j]);
                }
                cnt += (unsigned)__popcll(bal);   // SGPR add, stays uniform
            }
        }
    }
    const unsigned C = cnt;                  // exact count (overflow detectable)

    float loss = 0.0f;
    bool have = false;

    if (C >= K_SEL && C <= CAPW) {
        wave_lgkm_wait();                    // list writes visible to own wave

        // ---- keys live in LDS already: 8 reads, one wait ----
        unsigned keys[8];
        #pragma unroll
        for (int it = 0; it < 8; ++it) {
            const unsigned i = lane + it * 64u;
            keys[it] = (i < C) ? list[i] : 0u;     // pad with min-key
        }

        // ---- common-prefix detection: skip degenerate leading radix passes ----
        unsigned mn = 0xFFFFFFFFu, mx = 0u;
        #pragma unroll
        for (int it = 0; it < 8; ++it) {
            const unsigned i = lane + it * 64u;
            if (i < C) { mn = min(mn, keys[it]); mx = max(mx, keys[it]); }
        }
        #pragma unroll
        for (int off = 32; off > 0; off >>= 1) {
            mn = min(mn, (unsigned)__shfl_xor((int)mn, off));
            mx = max(mx, (unsigned)__shfl_xor((int)mx, off));
        }
        const unsigned diff = mn ^ mx;
        const int b0i = (diff == 0u) ? 3 : (__clz(diff) >> 3);   // first differing byte
        unsigned prefix = (b0i == 0) ? 0u : (mn >> (32 - 8 * b0i));
        unsigned kr = K_SEL;

        for (int pass = b0i; pass < 4; ++pass) {
            *reinterpret_cast<uint4*>(&hist[lane * 4]) = make_uint4(0, 0, 0, 0);
            wave_lgkm_wait();
            const int shift = 24 - 8 * pass;
            #pragma unroll
            for (int it = 0; it < 8; ++it) {
                unsigned k = keys[it];
                bool mm = (lane + it * 64u < C) &&
                          (pass == 0 || (k >> (shift + 8)) == prefix);
                if (mm) atomicAdd(&hist[(k >> shift) & 0xFFu], 1u);
            }
            wave_lgkm_wait();
            uint4 h = *reinterpret_cast<const uint4*>(&hist[lane * 4]);
            unsigned hb[4] = {h.x, h.y, h.z, h.w};
            unsigned s_local = hb[0] + hb[1] + hb[2] + hb[3];
            unsigned suf = s_local;                // suffix-scan over lanes
            #pragma unroll
            for (int off = 1; off < 64; off <<= 1) {
                unsigned o = __shfl_down(suf, off);
                suf += (lane + off < 64) ? o : 0u;
            }
            unsigned acc_above = suf - s_local;
            int foundc = -1; unsigned f_abv = 0;
            #pragma unroll
            for (int c = 3; c >= 0; --c) {
                unsigned S = acc_above + hb[c];
                if (acc_above < kr && S >= kr) { foundc = c; f_abv = acc_above; }
                acc_above = S;
            }
            bool win = (foundc >= 0);
            unsigned long long bal = __ballot(win);
            int wl = __ffsll((long long)bal) - 1;
            unsigned np = win ? ((prefix << 8) | (unsigned)(lane * 4 + foundc)) : 0u;
            unsigned nk = win ? (kr - f_abv) : 0u;
            prefix = __shfl(np, wl);
            kr     = __shfl(nk, wl);
        }
        const unsigned tkey = prefix, krem = kr;

        int facc = 0;                              // fixed-point, order-independent
        #pragma unroll
        for (int it = 0; it < 8; ++it) {
            unsigned k = keys[it];
            if ((lane + it * 64u) < C && k > tkey) {
                float ww = key2f(k) + 1.0f;
                facc += (int)(ww * ww * SCALE + 0.5f);
            }
        }
        #pragma unroll
        for (int off = 32; off > 0; off >>= 1) facc += __shfl_down(facc, off);
        if (lane == 0) {
            float tv    = key2f(tkey) + 1.0f;
            float total = (float)facc * (1.0f / SCALE) + (float)krem * tv * tv;
            float pd    = rp[target] - 1.0f;
            loss = DELTA_W * pd * pd + total * (1.0f / (float)K_SEL);
            have = true;
        }
    } else {
        // ---- fallback: exact full-row radix (never taken for Gaussian bench data) ----
        unsigned prefix = 0u, kr = K_SEL;
        for (int pass = 0; pass < 4; ++pass) {
            *reinterpret_cast<uint4*>(&hist[lane * 4]) = make_uint4(0, 0, 0, 0);
            wave_lgkm_wait();
            const int shift = 24 - 8 * pass;
            for (int it = 0; it < N / 64; ++it) {
                int i = lane + it * 64;
                unsigned k = f2key(rp[i]);
                if (i == target) k = 0u;
                bool mm = (pass == 0) || ((k >> (shift + 8)) == prefix);
                if (mm) atomicAdd(&hist[(k >> shift) & 0xFFu], 1u);
            }
            wave_lgkm_wait();
            uint4 h = *reinterpret_cast<const uint4*>(&hist[lane * 4]);
            unsigned hb[4] = {h.x, h.y, h.z, h.w};
            unsigned s_local = hb[0] + hb[1] + hb[2] + hb[3];
            unsigned suf = s_local;
            #pragma unroll
            for (int off = 1; off < 64; off <<= 1) {
                unsigned o = __shfl_down(suf, off);
                suf += (lane + off < 64) ? o : 0u;
            }
            unsigned acc_above = suf - s_local;
            int foundc = -1; unsigned f_abv = 0;
            #pragma unroll
            for (int c = 3; c >= 0; --c) {
                unsigned S = acc_above + hb[c];
                if (acc_above < kr && S >= kr) { foundc = c; f_abv = acc_above; }
                acc_above = S;
            }
            bool win = (foundc >= 0);
            unsigned long long bal = __ballot(win);
            int wl = __ffsll((long long)bal) - 1;
            unsigned np = win ? ((prefix << 8) | (unsigned)(lane * 4 + foundc)) : 0u;
            unsigned nk = win ? (kr - f_abv) : 0u;
            prefix = __shfl(np, wl);
            kr     = __shfl(nk, wl);
        }
        const unsigned tkey = prefix, krem = kr;

        int facc = 0;
        for (int it = 0; it < N / 64; ++it) {
            int i = lane + it * 64;
            unsigned k = f2key(rp[i]);
            if (i == target) k = 0u;
            if (k > tkey) { float ww = key2f(k) + 1.0f; facc += (int)(ww * ww * SCALE + 0.5f); }
        }
        #pragma unroll
        for (int off = 32; off > 0; off >>= 1) facc += __shfl_down(facc, off);
        if (lane == 0) {
            float tv    = key2f(tkey) + 1.0f;
            float total = (float)facc * (1.0f / SCALE) + (float)krem * tv * tv;
            float pd    = rp[target] - 1.0f;
            loss = DELTA_W * pd * pd + total * (1.0f / (float)K_SEL);
            have = true;
        }
    }

    if (have) row_loss[row] = loss;
}

__global__ __launch_bounds__(256) void final_reduce(
    const float* __restrict__ rl, float* __restrict__ out)
{
    int tid = threadIdx.x;
    float s = 0.0f;
    for (int i = tid; i < M; i += 256) s += rl[i];   // fixed order -> deterministic
    __shared__ float wp[4];
    int lane = tid & 63, wv = tid >> 6;
    #pragma unroll
    for (int off = 32; off > 0; off >>= 1) s += __shfl_down(s, off);
    if (lane == 0) wp[wv] = s;
    __syncthreads();
    if (tid == 0) out[0] = (wp[0] + wp[1] + wp[2] + wp[3]) / (float)M;
}

extern "C" void kernel_launch(void* const* d_in, const int* in_sizes, int n_in,
                              void* d_out, int out_size, void* d_ws, size_t ws_size,
                              hipStream_t stream) {
    const float* inp = (const float*)d_in[0];
    const int*   tgt = (const int*)d_in[1];
    float* out = (float*)d_out;
    float* row_loss = (float*)d_ws;      // 16 KiB of workspace

    fused_row_loss<<<M / 4, NT, 0, stream>>>(inp, tgt, row_loss);
    final_reduce<<<1, 256, 0, stream>>>(row_loss, out);
}